// Round 6
// baseline (695.522 us; speedup 1.0000x reference)
//
#include <hip/hip_runtime.h>
#include <hip/hip_bf16.h>

typedef unsigned short u16;
typedef unsigned int u32;
typedef short s16x8 __attribute__((ext_vector_type(8)));
typedef short s16x4 __attribute__((ext_vector_type(4)));
typedef float f32x4 __attribute__((ext_vector_type(4)));

#define NB 8
#define NT 2048
#define NC 512
#define NH 512

#if __has_builtin(__builtin_amdgcn_mfma_f32_16x16x16_bf16)
#define MFMA_PV(va, pb, c) __builtin_amdgcn_mfma_f32_16x16x16_bf16(va, pb, c, 0, 0, 0)
#else
#define MFMA_PV(va, pb, c) __builtin_amdgcn_mfma_f32_16x16x16bf16_1k(va, pb, c, 0, 0, 0)
#endif

__device__ __forceinline__ u16 f2bf(float f) {
  unsigned u = __float_as_uint(f);
  u += 0x7FFFu + ((u >> 16) & 1u);   // round-to-nearest-even
  return (u16)(u >> 16);
}

// async 16B global->LDS (dest = wave-uniform base + lane*16, src per-lane)
__device__ __forceinline__ void gld16(const u16* src, u16* lds_dst) {
  __builtin_amdgcn_global_load_lds(
      (const __attribute__((address_space(1))) u32*)src,
      (__attribute__((address_space(3))) u32*)lds_dst, 16, 0, 0);
}

// ---------------- K0: W [C][H] fp32 -> WT [H][C] bf16 ----------------
__global__ __launch_bounds__(256) void wt_kernel(const float* __restrict__ W,
                                                 u16* __restrict__ WT) {
  __shared__ float tile[32][33];
  const int x = threadIdx.x & 31;
  const int y = threadIdx.x >> 5;
  const int k0 = blockIdx.x * 32, h0 = blockIdx.y * 32;
#pragma unroll
  for (int p = 0; p < 4; ++p)
    tile[y + 8 * p][x] = W[(size_t)(k0 + y + 8 * p) * NH + h0 + x];
  __syncthreads();
#pragma unroll
  for (int p = 0; p < 4; ++p)
    WT[(size_t)(h0 + y + 8 * p) * NC + k0 + x] = f2bf(tile[x][y + 8 * p]);
}

// ---------------- K1: Y = X @ W + b ----------------
__global__ __launch_bounds__(256) void proj_kernel(const float* __restrict__ X,
                                                   const u16* __restrict__ WT,
                                                   const float* __restrict__ bias,
                                                   u16* __restrict__ Y) {
  __shared__ __align__(16) u16 Asub[128 * 40];
  __shared__ __align__(16) u16 Bsub[128 * 40];
  const int t = threadIdx.x;
  const int lane = t & 63;
  const int w = t >> 6;
  const int l16 = lane & 15;
  const int ko8 = (lane >> 4) * 8;
  const int m0 = blockIdx.y * 128;
  const int n0 = blockIdx.x * 128;
  const int wr = (w >> 1) * 64, wc = (w & 1) * 64;
  f32x4 acc[4][4] = {};

  for (int kt = 0; kt < 16; ++kt) {
    const int k0 = kt * 32;
#pragma unroll
    for (int p = 0; p < 4; ++p) {
      int c = t + 256 * p;
      int r = c >> 3, cc = (c & 7) * 4;
      const float4 v = *(const float4*)&X[(size_t)(m0 + r) * NC + k0 + cc];
      ushort4 bb;
      bb.x = f2bf(v.x); bb.y = f2bf(v.y); bb.z = f2bf(v.z); bb.w = f2bf(v.w);
      *(ushort4*)&Asub[r * 40 + cc] = bb;
    }
#pragma unroll
    for (int p = 0; p < 2; ++p) {
      int c = t + 256 * p;
      int r = c >> 2, cc = (c & 3) * 8;
      *(int4*)&Bsub[r * 40 + cc] = *(const int4*)&WT[(size_t)(n0 + r) * NC + k0 + cc];
    }
    __syncthreads();
    s16x8 af[4], bf[4];
#pragma unroll
    for (int i = 0; i < 4; ++i)
      af[i] = *(const s16x8*)&Asub[(wr + i * 16 + l16) * 40 + ko8];
#pragma unroll
    for (int j = 0; j < 4; ++j)
      bf[j] = *(const s16x8*)&Bsub[(wc + j * 16 + l16) * 40 + ko8];
#pragma unroll
    for (int i = 0; i < 4; ++i)
#pragma unroll
      for (int j = 0; j < 4; ++j)
        acc[i][j] = __builtin_amdgcn_mfma_f32_16x16x32_bf16(af[i], bf[j], acc[i][j], 0, 0, 0);
    __syncthreads();
  }
  const int rg = (lane >> 4) * 4;
#pragma unroll
  for (int i = 0; i < 4; ++i)
#pragma unroll
    for (int j = 0; j < 4; ++j) {
      const int col = n0 + wc + j * 16 + l16;
      const float bcol = bias[col];
#pragma unroll
      for (int jj = 0; jj < 4; ++jj) {
        const int row = m0 + wr + i * 16 + rg + jj;
        Y[(size_t)row * NH + col] = f2bf(acc[i][j][jj] + bcol);
      }
    }
}

// ---------------- K2: Vp [B][T][H] bf16 -> VpT [B][H][T] bf16 ----------------
__global__ __launch_bounds__(256) void vt_kernel(const u16* __restrict__ Vp,
                                                 u16* __restrict__ VpT) {
  __shared__ u16 tile[32][33];
  const int x = threadIdx.x & 31;
  const int y = threadIdx.x >> 5;
  const int t0 = blockIdx.x * 32, h0 = blockIdx.y * 32, b = blockIdx.z;
  const u16* src = Vp + (size_t)b * NT * NH;
  u16* dst = VpT + (size_t)b * NH * NT;
#pragma unroll
  for (int p = 0; p < 4; ++p)
    tile[y + 8 * p][x] = src[(size_t)(t0 + y + 8 * p) * NH + h0 + x];
  __syncthreads();
#pragma unroll
  for (int p = 0; p < 4; ++p)
    dst[(size_t)(h0 + y + 8 * p) * NT + t0 + x] = tile[x][y + 8 * p];
}

// ---------------- K3a: flash partial, 3-way kv-split, H-split waves ----------
// grid (NB, NT/32, 3). block 256 = 4 waves: w = wh*2 + wq.
//   wq in {0,1}: 16 q rows each (32 q rows per block)
//   wh in {0,1}: 256-h half of the PV accumulator (QK^T duplicated per wh)
// K in LDS (KVBLK=16, double-buffered, 32 KB), staged via global_load_lds,
// fragment-order: frag ks at u16 [ks*512 + lane*8] = K[kv0+l16][ks*32+g*8..+7].
// V^T read DIRECTLY from global (L1/L2-resident): no V LDS, no conflicts.
// QK: S^T[16 kv][16 q] per wave; softmax in-register (lane q=l16, kv=g*4+j);
// P packs directly into 16x16x16 B-frag; PV: 16 tiles over 256 h.
// Unnormalized O + (m,l) per row; merged by merge3_kernel.
__global__ __launch_bounds__(256, 3) void flash_partial3(const u16* __restrict__ Qp,
                                                         const u16* __restrict__ Kp,
                                                         const u16* __restrict__ VpT,
                                                         float* __restrict__ O0,
                                                         float* __restrict__ O1,
                                                         float* __restrict__ O2,
                                                         float* __restrict__ mlws) {
  __shared__ __align__(16) u16 Klds[2][16 * 512];   // 16 KB each

  const int t = threadIdx.x;
  const int lane = t & 63;
  const int w = t >> 6;
  const int wq = w & 1;
  const int wh = w >> 1;
  const int l16 = lane & 15;
  const int g = lane >> 4;
  const int g8 = g * 8;
  const int b = blockIdx.x;
  const int q0 = blockIdx.y * 32;
  const int z = blockIdx.z;
  const int qg = q0 + wq * 16 + l16;
  const int ntiles = (z < 2) ? 43 : 42;     // 43+43+42 = 128 tiles of 16 kv
  const int kvbase = z * 688;               // 43*16
  const float kscale = 0.044194173824159216f;  // 1/sqrt(512)

  // Q fragments (B-operand of 16x16x32): lane holds Q[q=l16][ks*32+g*8..+7]
  s16x8 qf[16];
  {
    const u16* qrow = Qp + (size_t)(b * NT + qg) * NH;
#pragma unroll
    for (int ks = 0; ks < 16; ++ks)
      qf[ks] = *(const s16x8*)&qrow[ks * 32 + g8];
  }

  f32x4 oacc[16] = {};   // O^T: h = wh*256 + ht*16 + g*4 + j, q = l16
  float m_run = -1e30f, l_run = 0.f;

  const u16* kbat = Kp + (size_t)(b * NT + kvbase) * NH;
  // V base for this wave's h-half; per-lane fixed part (l16 row, g*4 kv)
  const u16* vbat = VpT + (size_t)b * NH * NT + (size_t)(wh * 256) * NT
                    + kvbase + g * 4;

  // stage K tile 'it' into buffer buf (4 gld16 per wave; 16 instrs/block)
#define STAGEK(buf, it)                                                  \
  {                                                                      \
    _Pragma("unroll")                                                    \
    for (int r = 0; r < 4; ++r) {                                        \
      const int i = w * 4 + r; /* frag id = ks */                        \
      gld16(kbat + (size_t)((it) * 16 + l16) * NH + i * 32 + g8,         \
            &Klds[buf][i * 512]);                                        \
    }                                                                    \
  }

  STAGEK(0, 0)
  __syncthreads();

  int pb = 0;
  for (int it = 0; it < ntiles; ++it) {
    if (it + 1 < ntiles) STAGEK(pb ^ 1, it + 1)
    // ---- QK^T: S^T[16 kv][16 q] ----
    f32x4 s0 = {};
#pragma unroll
    for (int ks = 0; ks < 16; ++ks) {
      s16x8 kf = *(const s16x8*)&Klds[pb][ks * 512 + lane * 8];
      s0 = __builtin_amdgcn_mfma_f32_16x16x32_bf16(kf, qf[ks], s0, 0, 0, 0);
    }
    // ---- softmax (in-register; lane's q = l16, kv = g*4+j) ----
    float pv[4];
#pragma unroll
    for (int j = 0; j < 4; ++j) pv[j] = s0[j] * kscale;
    float mx = fmaxf(fmaxf(pv[0], pv[1]), fmaxf(pv[2], pv[3]));
    mx = fmaxf(mx, __shfl_xor(mx, 16, 64));
    mx = fmaxf(mx, __shfl_xor(mx, 32, 64));
    if (__any(mx > m_run)) {
      const float m_new = fmaxf(m_run, mx);
      const float scale = __expf(m_run - m_new);
#pragma unroll
      for (int ht = 0; ht < 16; ++ht) {
        oacc[ht][0] *= scale; oacc[ht][1] *= scale;
        oacc[ht][2] *= scale; oacc[ht][3] *= scale;
      }
      l_run *= scale;
      m_run = m_new;
    }
    float ts = 0.f;
#pragma unroll
    for (int j = 0; j < 4; ++j) { pv[j] = __expf(pv[j] - m_run); ts += pv[j]; }
    ts += __shfl_xor(ts, 16, 64);
    ts += __shfl_xor(ts, 32, 64);
    l_run += ts;
    // ---- P direct pack: B-frag of 16x16x16 (k=g*4+j, col=l16) ----
    union { u32 u[2]; s16x4 v; } pf;
    pf.u[0] = ((u32)f2bf(pv[1]) << 16) | f2bf(pv[0]);
    pf.u[1] = ((u32)f2bf(pv[3]) << 16) | f2bf(pv[2]);
    // ---- PV: O^T[h][q] += V^T[h][kv] @ P^T[kv][q], V direct from L1/L2 ----
    const u16* vit = vbat + it * 16;
#pragma unroll
    for (int ht = 0; ht < 16; ++ht) {
      s16x4 vf = *(const s16x4*)&vit[(size_t)(ht * 16 + l16) * NT];
      oacc[ht] = MFMA_PV(vf, pf.v, oacc[ht]);
    }
    __syncthreads();
    pb ^= 1;
  }
  // ---- epilogue: UNNORMALIZED O + (m,l) ----
  float* Oz = (z == 0) ? O0 : (z == 1) ? O1 : O2;
  float* obase = Oz + (size_t)(b * NT + qg) * NH + wh * 256;
#pragma unroll
  for (int ht = 0; ht < 16; ++ht) {
    float4 st;
    st.x = oacc[ht][0]; st.y = oacc[ht][1];
    st.z = oacc[ht][2]; st.w = oacc[ht][3];
    *(float4*)&obase[ht * 16 + g * 4] = st;
  }
  if (wh == 0 && g == 0) {
    const size_t row = (size_t)b * NT + qg;
    mlws[row * 6 + z * 2 + 0] = m_run;
    mlws[row * 6 + z * 2 + 1] = l_run;
  }
#undef STAGEK
}

// ---------------- K3b: merge three kv-third partials ----------------
__global__ __launch_bounds__(128) void merge3_kernel(float* __restrict__ out,
                                                     const float* __restrict__ O1,
                                                     const float* __restrict__ O2,
                                                     const float* __restrict__ mlws) {
  const size_t row = blockIdx.x;
  const float m0 = mlws[row * 6 + 0], l0 = mlws[row * 6 + 1];
  const float m1 = mlws[row * 6 + 2], l1 = mlws[row * 6 + 3];
  const float m2 = mlws[row * 6 + 4], l2 = mlws[row * 6 + 5];
  const float m = fmaxf(fmaxf(m0, m1), m2);
  const float a0 = __expf(m0 - m), a1 = __expf(m1 - m), a2 = __expf(m2 - m);
  const float inv = 1.f / (a0 * l0 + a1 * l1 + a2 * l2);
  const float c0 = a0 * inv, c1 = a1 * inv, c2 = a2 * inv;
  const size_t idx = row * NH + threadIdx.x * 4;
  float4 o0 = *(const float4*)&out[idx];
  float4 o1 = *(const float4*)&O1[idx];
  float4 o2 = *(const float4*)&O2[idx];
  float4 r;
  r.x = c0 * o0.x + c1 * o1.x + c2 * o2.x;
  r.y = c0 * o0.y + c1 * o1.y + c2 * o2.y;
  r.z = c0 * o0.z + c1 * o1.z + c2 * o2.z;
  r.w = c0 * o0.w + c1 * o1.w + c2 * o2.w;
  *(float4*)&out[idx] = r;
}

// ---------------- K3-fallback: R4 single-pass flash (if ws too small) --------
__global__ __launch_bounds__(256, 1) void flash_kernel(const u16* __restrict__ Qp,
                                                       const u16* __restrict__ Kp,
                                                       const u16* __restrict__ VpT,
                                                       float* __restrict__ out) {
  __shared__ __align__(16) u16 Klds[2][32 * 512];
  __shared__ __align__(16) u16 Vlds[2][32 * 512];

  const int t = threadIdx.x;
  const int lane = t & 63;
  const int w = t >> 6;
  const int l16 = lane & 15;
  const int g = lane >> 4;
  const int g8 = g * 8;
  const int b = blockIdx.x;
  const int q0 = blockIdx.y * 64;
  const int qg = q0 + w * 16 + l16;
  const float kscale = 0.044194173824159216f;

  s16x8 qf[16];
  {
    const u16* qrow = Qp + (size_t)(b * NT + qg) * NH;
#pragma unroll
    for (int ks = 0; ks < 16; ++ks)
      qf[ks] = *(const s16x8*)&qrow[ks * 32 + g8];
  }
  f32x4 oacc[32] = {};
  float m_run = -1e30f, l_run = 0.f;
  const u16* kbat = Kp + (size_t)b * NT * NH;
  const u16* vbat = VpT + (size_t)b * NH * NT;

#pragma unroll
  for (int r = 0; r < 8; ++r) {
    const int i = w * 8 + r;
    gld16(kbat + (size_t)(((i & 1) << 4) + l16) * NH + ((i >> 1) << 5) + g8,
          &Klds[0][i * 512]);
    gld16(vbat + (size_t)(i * 16 + l16) * NT + g8, &Vlds[0][i * 512]);
  }
  __syncthreads();

  int pb = 0;
  for (int it = 0; it < 64; ++it) {
    if (it < 63) {
      const int kv1 = (it + 1) * 32;
      const int nb = pb ^ 1;
#pragma unroll
      for (int r = 0; r < 8; ++r) {
        const int i = w * 8 + r;
        gld16(kbat + (size_t)(kv1 + ((i & 1) << 4) + l16) * NH + ((i >> 1) << 5) + g8,
              &Klds[nb][i * 512]);
        gld16(vbat + (size_t)(i * 16 + l16) * NT + kv1 + g8, &Vlds[nb][i * 512]);
      }
    }
    f32x4 s0 = {}, s1 = {};
#pragma unroll
    for (int ks = 0; ks < 16; ++ks) {
      s16x8 kf0 = *(const s16x8*)&Klds[pb][(ks * 2 + 0) * 512 + lane * 8];
      s16x8 kf1 = *(const s16x8*)&Klds[pb][(ks * 2 + 1) * 512 + lane * 8];
      s0 = __builtin_amdgcn_mfma_f32_16x16x32_bf16(kf0, qf[ks], s0, 0, 0, 0);
      s1 = __builtin_amdgcn_mfma_f32_16x16x32_bf16(kf1, qf[ks], s1, 0, 0, 0);
    }
    float pv[8];
#pragma unroll
    for (int j = 0; j < 4; ++j) { pv[j] = s0[j] * kscale; pv[4 + j] = s1[j] * kscale; }
    float mx = pv[0];
#pragma unroll
    for (int j = 1; j < 8; ++j) mx = fmaxf(mx, pv[j]);
    mx = fmaxf(mx, __shfl_xor(mx, 16, 64));
    mx = fmaxf(mx, __shfl_xor(mx, 32, 64));
    if (__any(mx > m_run)) {
      const float m_new = fmaxf(m_run, mx);
      const float scale = __expf(m_run - m_new);
#pragma unroll
      for (int ht = 0; ht < 32; ++ht) {
        oacc[ht][0] *= scale; oacc[ht][1] *= scale;
        oacc[ht][2] *= scale; oacc[ht][3] *= scale;
      }
      l_run *= scale;
      m_run = m_new;
    }
    float ts = 0.f;
#pragma unroll
    for (int j = 0; j < 8; ++j) { pv[j] = __expf(pv[j] - m_run); ts += pv[j]; }
    ts += __shfl_xor(ts, 16, 64);
    ts += __shfl_xor(ts, 32, 64);
    l_run += ts;
    u32 b0 = ((u32)f2bf(pv[1]) << 16) | f2bf(pv[0]);
    u32 b1 = ((u32)f2bf(pv[3]) << 16) | f2bf(pv[2]);
    u32 b2 = ((u32)f2bf(pv[5]) << 16) | f2bf(pv[4]);
    u32 b3 = ((u32)f2bf(pv[7]) << 16) | f2bf(pv[6]);
    const int srcA = (g & 1) * 32 + l16;
    const int srcB = srcA + 16;
    u32 x0 = (u32)__shfl((int)b0, srcA, 64);
    u32 x1 = (u32)__shfl((int)b1, srcA, 64);
    u32 x2 = (u32)__shfl((int)b2, srcA, 64);
    u32 x3 = (u32)__shfl((int)b3, srcA, 64);
    u32 y0 = (u32)__shfl((int)b0, srcB, 64);
    u32 y1 = (u32)__shfl((int)b1, srcB, 64);
    u32 y2 = (u32)__shfl((int)b2, srcB, 64);
    u32 y3 = (u32)__shfl((int)b3, srcB, 64);
    const bool hi = (lane >> 5) & 1;
    union { u32 u[4]; s16x8 v; } pf;
    pf.u[0] = hi ? x2 : x0;
    pf.u[1] = hi ? x3 : x1;
    pf.u[2] = hi ? y2 : y0;
    pf.u[3] = hi ? y3 : y1;
#pragma unroll
    for (int ht = 0; ht < 32; ++ht) {
      s16x8 vf = *(const s16x8*)&Vlds[pb][ht * 512 + lane * 8];
      oacc[ht] = __builtin_amdgcn_mfma_f32_16x16x32_bf16(vf, pf.v, oacc[ht], 0, 0, 0);
    }
    __syncthreads();
    pb ^= 1;
  }
  const float inv = 1.f / l_run;
  float* obase = out + (size_t)(b * NT + qg) * NH;
#pragma unroll
  for (int ht = 0; ht < 32; ++ht) {
    float4 st;
    st.x = oacc[ht][0] * inv; st.y = oacc[ht][1] * inv;
    st.z = oacc[ht][2] * inv; st.w = oacc[ht][3] * inv;
    *(float4*)&obase[ht * 16 + g * 4] = st;
  }
}

extern "C" void kernel_launch(void* const* d_in, const int* in_sizes, int n_in,
                              void* d_out, int out_size, void* d_ws, size_t ws_size,
                              hipStream_t stream) {
  (void)in_sizes; (void)n_in; (void)out_size;
  const float* q  = (const float*)d_in[0];
  const float* k  = (const float*)d_in[1];
  const float* v  = (const float*)d_in[2];
  const float* Wq = (const float*)d_in[3];
  const float* bq = (const float*)d_in[4];
  const float* Wk = (const float*)d_in[5];
  const float* bk = (const float*)d_in[6];
  const float* Wv = (const float*)d_in[7];
  const float* bv = (const float*)d_in[8];
  float* out = (float*)d_out;

  u16* ws   = (u16*)d_ws;
  u16* WqT  = ws;
  u16* WkT  = WqT + (size_t)NC * NH;
  u16* WvT  = WkT + (size_t)NC * NH;
  u16* Qp   = WvT + (size_t)NC * NH;
  u16* Kp   = Qp + (size_t)NB * NT * NH;
  u16* Vp   = Kp + (size_t)NB * NT * NH;
  u16* VpT  = Vp + (size_t)NB * NT * NH;
  u16* endb = VpT + (size_t)NB * NT * NH;
  // kv-split extras: O1, O2 partials (f32, 32 MB each) + mlws (6 f32/row)
  float* O1   = (float*)endb;
  float* O2   = O1 + (size_t)NB * NT * NH;
  float* mlws = O2 + (size_t)NB * NT * NH;
  const size_t need = (size_t)((char*)(mlws + (size_t)NB * NT * 6) - (char*)d_ws);

  wt_kernel<<<dim3(16, 16), 256, 0, stream>>>(Wq, WqT);
  wt_kernel<<<dim3(16, 16), 256, 0, stream>>>(Wk, WkT);
  wt_kernel<<<dim3(16, 16), 256, 0, stream>>>(Wv, WvT);

  proj_kernel<<<dim3(4, 128), 256, 0, stream>>>(q, WqT, bq, Qp);
  proj_kernel<<<dim3(4, 128), 256, 0, stream>>>(k, WkT, bk, Kp);
  proj_kernel<<<dim3(4, 128), 256, 0, stream>>>(v, WvT, bv, Vp);

  vt_kernel<<<dim3(64, 16, NB), 256, 0, stream>>>(Vp, VpT);

  if (ws_size >= need) {
    flash_partial3<<<dim3(NB, NT / 32, 3), 256, 0, stream>>>(Qp, Kp, VpT, out, O1, O2, mlws);
    merge3_kernel<<<dim3(NB * NT), 128, 0, stream>>>(out, O1, O2, mlws);
  } else {
    flash_kernel<<<dim3(NB, NT / 64), 256, 0, stream>>>(Qp, Kp, VpT, out);
  }
}

// Round 7
// 234.355 us; speedup vs baseline: 2.9678x; 2.9678x over previous
//
#include <hip/hip_runtime.h>
#include <hip/hip_bf16.h>

typedef unsigned short u16;
typedef unsigned int u32;
typedef short s16x8 __attribute__((ext_vector_type(8)));
typedef float f32x4 __attribute__((ext_vector_type(4)));

#define NB 8
#define NT 2048
#define NC 512
#define NH 512

__device__ __forceinline__ u16 f2bf(float f) {
  unsigned u = __float_as_uint(f);
  u += 0x7FFFu + ((u >> 16) & 1u);   // round-to-nearest-even
  return (u16)(u >> 16);
}

// async 16B global->LDS (dest = wave-uniform base + lane*16, src per-lane)
__device__ __forceinline__ void gld16(const u16* src, u16* lds_dst) {
  __builtin_amdgcn_global_load_lds(
      (const __attribute__((address_space(1))) u32*)src,
      (__attribute__((address_space(3))) u32*)lds_dst, 16, 0, 0);
}

// ---------------- K0: W [C][H] fp32 -> WT [H][C] bf16 ----------------
__global__ __launch_bounds__(256) void wt_kernel(const float* __restrict__ W,
                                                 u16* __restrict__ WT) {
  __shared__ float tile[32][33];
  const int x = threadIdx.x & 31;
  const int y = threadIdx.x >> 5;
  const int k0 = blockIdx.x * 32, h0 = blockIdx.y * 32;
#pragma unroll
  for (int p = 0; p < 4; ++p)
    tile[y + 8 * p][x] = W[(size_t)(k0 + y + 8 * p) * NH + h0 + x];
  __syncthreads();
#pragma unroll
  for (int p = 0; p < 4; ++p)
    WT[(size_t)(h0 + y + 8 * p) * NC + k0 + x] = f2bf(tile[x][y + 8 * p]);
}

// ---------------- K1: Y = X @ W + b ----------------
__global__ __launch_bounds__(256) void proj_kernel(const float* __restrict__ X,
                                                   const u16* __restrict__ WT,
                                                   const float* __restrict__ bias,
                                                   u16* __restrict__ Y) {
  __shared__ __align__(16) u16 Asub[128 * 40];
  __shared__ __align__(16) u16 Bsub[128 * 40];
  const int t = threadIdx.x;
  const int lane = t & 63;
  const int w = t >> 6;
  const int l16 = lane & 15;
  const int ko8 = (lane >> 4) * 8;
  const int m0 = blockIdx.y * 128;
  const int n0 = blockIdx.x * 128;
  const int wr = (w >> 1) * 64, wc = (w & 1) * 64;
  f32x4 acc[4][4] = {};

  for (int kt = 0; kt < 16; ++kt) {
    const int k0 = kt * 32;
#pragma unroll
    for (int p = 0; p < 4; ++p) {
      int c = t + 256 * p;
      int r = c >> 3, cc = (c & 7) * 4;
      const float4 v = *(const float4*)&X[(size_t)(m0 + r) * NC + k0 + cc];
      ushort4 bb;
      bb.x = f2bf(v.x); bb.y = f2bf(v.y); bb.z = f2bf(v.z); bb.w = f2bf(v.w);
      *(ushort4*)&Asub[r * 40 + cc] = bb;
    }
#pragma unroll
    for (int p = 0; p < 2; ++p) {
      int c = t + 256 * p;
      int r = c >> 2, cc = (c & 3) * 8;
      *(int4*)&Bsub[r * 40 + cc] = *(const int4*)&WT[(size_t)(n0 + r) * NC + k0 + cc];
    }
    __syncthreads();
    s16x8 af[4], bf[4];
#pragma unroll
    for (int i = 0; i < 4; ++i)
      af[i] = *(const s16x8*)&Asub[(wr + i * 16 + l16) * 40 + ko8];
#pragma unroll
    for (int j = 0; j < 4; ++j)
      bf[j] = *(const s16x8*)&Bsub[(wc + j * 16 + l16) * 40 + ko8];
#pragma unroll
    for (int i = 0; i < 4; ++i)
#pragma unroll
      for (int j = 0; j < 4; ++j)
        acc[i][j] = __builtin_amdgcn_mfma_f32_16x16x32_bf16(af[i], bf[j], acc[i][j], 0, 0, 0);
    __syncthreads();
  }
  const int rg = (lane >> 4) * 4;
#pragma unroll
  for (int i = 0; i < 4; ++i)
#pragma unroll
    for (int j = 0; j < 4; ++j) {
      const int col = n0 + wc + j * 16 + l16;
      const float bcol = bias[col];
#pragma unroll
      for (int jj = 0; jj < 4; ++jj) {
        const int row = m0 + wr + i * 16 + rg + jj;
        Y[(size_t)row * NH + col] = f2bf(acc[i][j][jj] + bcol);
      }
    }
}

// ---------------- K2: Vp [B][T][H] bf16 -> VpT [B][H][T] bf16 ----------------
__global__ __launch_bounds__(256) void vt_kernel(const u16* __restrict__ Vp,
                                                 u16* __restrict__ VpT) {
  __shared__ u16 tile[32][33];
  const int x = threadIdx.x & 31;
  const int y = threadIdx.x >> 5;
  const int t0 = blockIdx.x * 32, h0 = blockIdx.y * 32, b = blockIdx.z;
  const u16* src = Vp + (size_t)b * NT * NH;
  u16* dst = VpT + (size_t)b * NH * NT;
#pragma unroll
  for (int p = 0; p < 4; ++p)
    tile[y + 8 * p][x] = src[(size_t)(t0 + y + 8 * p) * NH + h0 + x];
  __syncthreads();
#pragma unroll
  for (int p = 0; p < 4; ++p)
    dst[(size_t)(h0 + y + 8 * p) * NT + t0 + x] = tile[x][y + 8 * p];
}

// ---------------- K3a: flash partial, QB=128, 2-way kv-split ----------------
// grid (NB=8, NT/128=16, 2). block 512 = 8 waves, each owns 16 q rows
// (QB=128/block). KVBLK=32, double-buffered K+V in LDS (128 KB, 1 block/CU).
// Inner loop identical to the verified R4 kernel (frag-order conflict-free
// LDS via global_load_lds, in-register softmax, 8-shuffle P pack, PV x32).
// KV traffic = 256 blocks x 2 MB = 512 MB (half of QB=64).
// Unnormalized O + (m,l); merged by merge_kernel.
__global__ __launch_bounds__(512, 2) void flash_partial(const u16* __restrict__ Qp,
                                                        const u16* __restrict__ Kp,
                                                        const u16* __restrict__ VpT,
                                                        float* __restrict__ O0,
                                                        float* __restrict__ O1,
                                                        float* __restrict__ mlws) {
  __shared__ __align__(16) u16 Klds[2][32 * 512];   // 32 KB each
  __shared__ __align__(16) u16 Vlds[2][32 * 512];   // 32 KB each

  const int t = threadIdx.x;
  const int lane = t & 63;
  const int w = t >> 6;               // 0..7: q-group
  const int l16 = lane & 15;
  const int g = lane >> 4;
  const int g8 = g * 8;
  const int b = blockIdx.x;
  const int q0 = blockIdx.y * 128;
  const int z = blockIdx.z;
  const int qg = q0 + w * 16 + l16;   // this lane's q row
  const float kscale = 0.044194173824159216f;  // 1/sqrt(512)

  // Q fragments (B-operand): lane holds Q[q=l16][d = ks*32 + g*8 .. +7]
  s16x8 qf[16];
  {
    const u16* qrow = Qp + (size_t)(b * NT + qg) * NH;
#pragma unroll
    for (int ks = 0; ks < 16; ++ks)
      qf[ks] = *(const s16x8*)&qrow[ks * 32 + g8];
  }

  f32x4 oacc[32] = {};                 // O^T: h = ht*16 + g*4 + j, q = l16
  float m_run = -1e30f, l_run = 0.f;

  const u16* kbat = Kp + (size_t)(b * NT + z * 1024) * NH;
  const u16* vbat = VpT + (size_t)b * NH * NT + z * 1024;

  // stage tile 'it' into buffer buf: 64 gld16 per block = 8 per wave (4K+4V)
#define STAGE(buf, it)                                                         \
  {                                                                            \
    _Pragma("unroll")                                                          \
    for (int r = 0; r < 4; ++r) {                                              \
      const int i = w * 4 + r;  /* 0..31 */                                    \
      /* K frag i: ks=i>>1, kb=i&1 -> K[kv0+kb*16+l16][ks*32+g*8..+7] */       \
      gld16(kbat + (size_t)((it) * 32 + ((i & 1) << 4) + l16) * NH             \
                 + ((i >> 1) << 5) + g8,                                       \
            &Klds[buf][i * 512]);                                              \
      /* V frag i=ht: V^T[ht*16+l16][kv0+g*8..+7] */                           \
      gld16(vbat + (size_t)(i * 16 + l16) * NT + (it) * 32 + g8,               \
            &Vlds[buf][i * 512]);                                              \
    }                                                                          \
  }

  STAGE(0, 0)
  __syncthreads();

  int pb = 0;
  for (int it = 0; it < 32; ++it) {
    if (it < 31) STAGE(pb ^ 1, it + 1)
    // ---- QK^T: S^T[32 kv][16 q] ----
    f32x4 s0 = {}, s1 = {};
#pragma unroll
    for (int ks = 0; ks < 16; ++ks) {
      s16x8 kf0 = *(const s16x8*)&Klds[pb][(ks * 2 + 0) * 512 + lane * 8];
      s16x8 kf1 = *(const s16x8*)&Klds[pb][(ks * 2 + 1) * 512 + lane * 8];
      s0 = __builtin_amdgcn_mfma_f32_16x16x32_bf16(kf0, qf[ks], s0, 0, 0, 0);
      s1 = __builtin_amdgcn_mfma_f32_16x16x32_bf16(kf1, qf[ks], s1, 0, 0, 0);
    }
    // ---- softmax (in-register; lane's q = l16) ----
    float pv[8];
#pragma unroll
    for (int j = 0; j < 4; ++j) { pv[j] = s0[j] * kscale; pv[4 + j] = s1[j] * kscale; }
    float mx = pv[0];
#pragma unroll
    for (int j = 1; j < 8; ++j) mx = fmaxf(mx, pv[j]);
    mx = fmaxf(mx, __shfl_xor(mx, 16, 64));
    mx = fmaxf(mx, __shfl_xor(mx, 32, 64));
    if (__any(mx > m_run)) {
      const float m_new = fmaxf(m_run, mx);
      const float scale = __expf(m_run - m_new);
#pragma unroll
      for (int ht = 0; ht < 32; ++ht) {
        oacc[ht][0] *= scale; oacc[ht][1] *= scale;
        oacc[ht][2] *= scale; oacc[ht][3] *= scale;
      }
      l_run *= scale;
      m_run = m_new;
    }
    float ts = 0.f;
#pragma unroll
    for (int j = 0; j < 8; ++j) { pv[j] = __expf(pv[j] - m_run); ts += pv[j]; }
    ts += __shfl_xor(ts, 16, 64);
    ts += __shfl_xor(ts, 32, 64);
    l_run += ts;
    // ---- P^T -> B-operand fragment (8 shuffles, verified R4 path) ----
    u32 b0 = ((u32)f2bf(pv[1]) << 16) | f2bf(pv[0]);
    u32 b1 = ((u32)f2bf(pv[3]) << 16) | f2bf(pv[2]);
    u32 b2 = ((u32)f2bf(pv[5]) << 16) | f2bf(pv[4]);
    u32 b3 = ((u32)f2bf(pv[7]) << 16) | f2bf(pv[6]);
    const int srcA = (g & 1) * 32 + l16;
    const int srcB = srcA + 16;
    u32 x0 = (u32)__shfl((int)b0, srcA, 64);
    u32 x1 = (u32)__shfl((int)b1, srcA, 64);
    u32 x2 = (u32)__shfl((int)b2, srcA, 64);
    u32 x3 = (u32)__shfl((int)b3, srcA, 64);
    u32 y0 = (u32)__shfl((int)b0, srcB, 64);
    u32 y1 = (u32)__shfl((int)b1, srcB, 64);
    u32 y2 = (u32)__shfl((int)b2, srcB, 64);
    u32 y3 = (u32)__shfl((int)b3, srcB, 64);
    const bool hi = (lane >> 5) & 1;
    union { u32 u[4]; s16x8 v; } pf;
    pf.u[0] = hi ? x2 : x0;
    pf.u[1] = hi ? x3 : x1;
    pf.u[2] = hi ? y2 : y0;
    pf.u[3] = hi ? y3 : y1;
    // ---- PV: O^T[h][q] += V^T[h][kv] @ P^T[kv][q] ----
#pragma unroll
    for (int ht = 0; ht < 32; ++ht) {
      s16x8 vf = *(const s16x8*)&Vlds[pb][ht * 512 + lane * 8];
      oacc[ht] = __builtin_amdgcn_mfma_f32_16x16x32_bf16(vf, pf.v, oacc[ht], 0, 0, 0);
    }
    __syncthreads();
    pb ^= 1;
  }
  // ---- epilogue: UNNORMALIZED O + (m,l) ----
  float* obase = (z ? O1 : O0) + (size_t)(b * NT + qg) * NH;
#pragma unroll
  for (int ht = 0; ht < 32; ++ht) {
    float4 st;
    st.x = oacc[ht][0]; st.y = oacc[ht][1];
    st.z = oacc[ht][2]; st.w = oacc[ht][3];
    *(float4*)&obase[ht * 16 + g * 4] = st;
  }
  if (g == 0) {
    const size_t row = (size_t)b * NT + qg;
    mlws[row * 4 + z * 2 + 0] = m_run;
    mlws[row * 4 + z * 2 + 1] = l_run;
  }
#undef STAGE
}

// ---------------- K3b: merge two kv-half partials ----------------
__global__ __launch_bounds__(128) void merge_kernel(float* __restrict__ out,
                                                    const float* __restrict__ O1,
                                                    const float* __restrict__ mlws) {
  const size_t row = blockIdx.x;
  const float m0 = mlws[row * 4 + 0], l0 = mlws[row * 4 + 1];
  const float m1 = mlws[row * 4 + 2], l1 = mlws[row * 4 + 3];
  const float m = fmaxf(m0, m1);
  const float a0 = __expf(m0 - m), a1 = __expf(m1 - m);
  const float inv = 1.f / (a0 * l0 + a1 * l1);
  const float c0 = a0 * inv, c1 = a1 * inv;
  const size_t idx = row * NH + threadIdx.x * 4;
  float4 o0 = *(const float4*)&out[idx];
  float4 o1 = *(const float4*)&O1[idx];
  float4 r;
  r.x = c0 * o0.x + c1 * o1.x;
  r.y = c0 * o0.y + c1 * o1.y;
  r.z = c0 * o0.z + c1 * o1.z;
  r.w = c0 * o0.w + c1 * o1.w;
  *(float4*)&out[idx] = r;
}

// ---------------- K3-fallback: R4 single-pass flash (if ws too small) --------
__global__ __launch_bounds__(256, 1) void flash_kernel(const u16* __restrict__ Qp,
                                                       const u16* __restrict__ Kp,
                                                       const u16* __restrict__ VpT,
                                                       float* __restrict__ out) {
  __shared__ __align__(16) u16 Klds[2][32 * 512];
  __shared__ __align__(16) u16 Vlds[2][32 * 512];

  const int t = threadIdx.x;
  const int lane = t & 63;
  const int w = t >> 6;
  const int l16 = lane & 15;
  const int g = lane >> 4;
  const int g8 = g * 8;
  const int b = blockIdx.x;
  const int q0 = blockIdx.y * 64;
  const int qg = q0 + w * 16 + l16;
  const float kscale = 0.044194173824159216f;

  s16x8 qf[16];
  {
    const u16* qrow = Qp + (size_t)(b * NT + qg) * NH;
#pragma unroll
    for (int ks = 0; ks < 16; ++ks)
      qf[ks] = *(const s16x8*)&qrow[ks * 32 + g8];
  }
  f32x4 oacc[32] = {};
  float m_run = -1e30f, l_run = 0.f;
  const u16* kbat = Kp + (size_t)b * NT * NH;
  const u16* vbat = VpT + (size_t)b * NH * NT;

#pragma unroll
  for (int r = 0; r < 8; ++r) {
    const int i = w * 8 + r;
    gld16(kbat + (size_t)(((i & 1) << 4) + l16) * NH + ((i >> 1) << 5) + g8,
          &Klds[0][i * 512]);
    gld16(vbat + (size_t)(i * 16 + l16) * NT + g8, &Vlds[0][i * 512]);
  }
  __syncthreads();

  int pb = 0;
  for (int it = 0; it < 64; ++it) {
    if (it < 63) {
      const int kv1 = (it + 1) * 32;
      const int nb = pb ^ 1;
#pragma unroll
      for (int r = 0; r < 8; ++r) {
        const int i = w * 8 + r;
        gld16(kbat + (size_t)(kv1 + ((i & 1) << 4) + l16) * NH + ((i >> 1) << 5) + g8,
              &Klds[nb][i * 512]);
        gld16(vbat + (size_t)(i * 16 + l16) * NT + kv1 + g8, &Vlds[nb][i * 512]);
      }
    }
    f32x4 s0 = {}, s1 = {};
#pragma unroll
    for (int ks = 0; ks < 16; ++ks) {
      s16x8 kf0 = *(const s16x8*)&Klds[pb][(ks * 2 + 0) * 512 + lane * 8];
      s16x8 kf1 = *(const s16x8*)&Klds[pb][(ks * 2 + 1) * 512 + lane * 8];
      s0 = __builtin_amdgcn_mfma_f32_16x16x32_bf16(kf0, qf[ks], s0, 0, 0, 0);
      s1 = __builtin_amdgcn_mfma_f32_16x16x32_bf16(kf1, qf[ks], s1, 0, 0, 0);
    }
    float pv[8];
#pragma unroll
    for (int j = 0; j < 4; ++j) { pv[j] = s0[j] * kscale; pv[4 + j] = s1[j] * kscale; }
    float mx = pv[0];
#pragma unroll
    for (int j = 1; j < 8; ++j) mx = fmaxf(mx, pv[j]);
    mx = fmaxf(mx, __shfl_xor(mx, 16, 64));
    mx = fmaxf(mx, __shfl_xor(mx, 32, 64));
    if (__any(mx > m_run)) {
      const float m_new = fmaxf(m_run, mx);
      const float scale = __expf(m_run - m_new);
#pragma unroll
      for (int ht = 0; ht < 32; ++ht) {
        oacc[ht][0] *= scale; oacc[ht][1] *= scale;
        oacc[ht][2] *= scale; oacc[ht][3] *= scale;
      }
      l_run *= scale;
      m_run = m_new;
    }
    float ts = 0.f;
#pragma unroll
    for (int j = 0; j < 8; ++j) { pv[j] = __expf(pv[j] - m_run); ts += pv[j]; }
    ts += __shfl_xor(ts, 16, 64);
    ts += __shfl_xor(ts, 32, 64);
    l_run += ts;
    u32 b0 = ((u32)f2bf(pv[1]) << 16) | f2bf(pv[0]);
    u32 b1 = ((u32)f2bf(pv[3]) << 16) | f2bf(pv[2]);
    u32 b2 = ((u32)f2bf(pv[5]) << 16) | f2bf(pv[4]);
    u32 b3 = ((u32)f2bf(pv[7]) << 16) | f2bf(pv[6]);
    const int srcA = (g & 1) * 32 + l16;
    const int srcB = srcA + 16;
    u32 x0 = (u32)__shfl((int)b0, srcA, 64);
    u32 x1 = (u32)__shfl((int)b1, srcA, 64);
    u32 x2 = (u32)__shfl((int)b2, srcA, 64);
    u32 x3 = (u32)__shfl((int)b3, srcA, 64);
    u32 y0 = (u32)__shfl((int)b0, srcB, 64);
    u32 y1 = (u32)__shfl((int)b1, srcB, 64);
    u32 y2 = (u32)__shfl((int)b2, srcB, 64);
    u32 y3 = (u32)__shfl((int)b3, srcB, 64);
    const bool hi = (lane >> 5) & 1;
    union { u32 u[4]; s16x8 v; } pf;
    pf.u[0] = hi ? x2 : x0;
    pf.u[1] = hi ? x3 : x1;
    pf.u[2] = hi ? y2 : y0;
    pf.u[3] = hi ? y3 : y1;
#pragma unroll
    for (int ht = 0; ht < 32; ++ht) {
      s16x8 vf = *(const s16x8*)&Vlds[pb][ht * 512 + lane * 8];
      oacc[ht] = __builtin_amdgcn_mfma_f32_16x16x32_bf16(vf, pf.v, oacc[ht], 0, 0, 0);
    }
    __syncthreads();
    pb ^= 1;
  }
  const float inv = 1.f / l_run;
  float* obase = out + (size_t)(b * NT + qg) * NH;
#pragma unroll
  for (int ht = 0; ht < 32; ++ht) {
    float4 st;
    st.x = oacc[ht][0] * inv; st.y = oacc[ht][1] * inv;
    st.z = oacc[ht][2] * inv; st.w = oacc[ht][3] * inv;
    *(float4*)&obase[ht * 16 + g * 4] = st;
  }
}

extern "C" void kernel_launch(void* const* d_in, const int* in_sizes, int n_in,
                              void* d_out, int out_size, void* d_ws, size_t ws_size,
                              hipStream_t stream) {
  (void)in_sizes; (void)n_in; (void)out_size;
  const float* q  = (const float*)d_in[0];
  const float* k  = (const float*)d_in[1];
  const float* v  = (const float*)d_in[2];
  const float* Wq = (const float*)d_in[3];
  const float* bq = (const float*)d_in[4];
  const float* Wk = (const float*)d_in[5];
  const float* bk = (const float*)d_in[6];
  const float* Wv = (const float*)d_in[7];
  const float* bv = (const float*)d_in[8];
  float* out = (float*)d_out;

  u16* ws   = (u16*)d_ws;
  u16* WqT  = ws;
  u16* WkT  = WqT + (size_t)NC * NH;
  u16* WvT  = WkT + (size_t)NC * NH;
  u16* Qp   = WvT + (size_t)NC * NH;
  u16* Kp   = Qp + (size_t)NB * NT * NH;
  u16* Vp   = Kp + (size_t)NB * NT * NH;
  u16* VpT  = Vp + (size_t)NB * NT * NH;
  u16* endb = VpT + (size_t)NB * NT * NH;
  // kv-split extras: O1 partial (f32, 32 MB) + mlws (4 f32/row)
  float* O1   = (float*)endb;
  float* mlws = O1 + (size_t)NB * NT * NH;
  const size_t need = (size_t)((char*)(mlws + (size_t)NB * NT * 4) - (char*)d_ws);

  wt_kernel<<<dim3(16, 16), 256, 0, stream>>>(Wq, WqT);
  wt_kernel<<<dim3(16, 16), 256, 0, stream>>>(Wk, WkT);
  wt_kernel<<<dim3(16, 16), 256, 0, stream>>>(Wv, WvT);

  proj_kernel<<<dim3(4, 128), 256, 0, stream>>>(q, WqT, bq, Qp);
  proj_kernel<<<dim3(4, 128), 256, 0, stream>>>(k, WkT, bk, Kp);
  proj_kernel<<<dim3(4, 128), 256, 0, stream>>>(v, WvT, bv, Vp);

  vt_kernel<<<dim3(64, 16, NB), 256, 0, stream>>>(Vp, VpT);

  if (ws_size >= need) {
    flash_partial<<<dim3(NB, NT / 128, 2), 512, 0, stream>>>(Qp, Kp, VpT, out, O1, mlws);
    merge_kernel<<<dim3(NB * NT), 128, 0, stream>>>(out, O1, mlws);
  } else {
    flash_kernel<<<dim3(NB, NT / 64), 256, 0, stream>>>(Qp, Kp, VpT, out);
  }
}

// Round 8
// 228.604 us; speedup vs baseline: 3.0425x; 1.0252x over previous
//
#include <hip/hip_runtime.h>
#include <hip/hip_bf16.h>

typedef unsigned short u16;
typedef unsigned int u32;
typedef short s16x8 __attribute__((ext_vector_type(8)));
typedef float f32x4 __attribute__((ext_vector_type(4)));

#define NB 8
#define NT 2048
#define NC 512
#define NH 512

__device__ __forceinline__ u16 f2bf(float f) {
  unsigned u = __float_as_uint(f);
  u += 0x7FFFu + ((u >> 16) & 1u);   // round-to-nearest-even
  return (u16)(u >> 16);
}

// async 16B global->LDS (dest = wave-uniform base + lane*16, src per-lane)
__device__ __forceinline__ void gld16(const u16* src, u16* lds_dst) {
  __builtin_amdgcn_global_load_lds(
      (const __attribute__((address_space(1))) u32*)src,
      (__attribute__((address_space(3))) u32*)lds_dst, 16, 0, 0);
}

// ---------------- K0: W [C][H] fp32 -> WT [H][C] bf16 ----------------
__global__ __launch_bounds__(256) void wt_kernel(const float* __restrict__ W,
                                                 u16* __restrict__ WT) {
  __shared__ float tile[32][33];
  const int x = threadIdx.x & 31;
  const int y = threadIdx.x >> 5;
  const int k0 = blockIdx.x * 32, h0 = blockIdx.y * 32;
#pragma unroll
  for (int p = 0; p < 4; ++p)
    tile[y + 8 * p][x] = W[(size_t)(k0 + y + 8 * p) * NH + h0 + x];
  __syncthreads();
#pragma unroll
  for (int p = 0; p < 4; ++p)
    WT[(size_t)(h0 + y + 8 * p) * NC + k0 + x] = f2bf(tile[x][y + 8 * p]);
}

// ---------------- K1: Y = X @ W + b  (T14 issue-early/write-late, dbuf LDS) --
// X fp32 [M][512], WT bf16 [N][K] (pre-transposed), Y bf16 [M][N].
// grid (4, 128), block 256 (4 waves). BM=BN=128, BK=32, 16 K-steps.
__global__ __launch_bounds__(256) void proj_kernel(const float* __restrict__ X,
                                                   const u16* __restrict__ WT,
                                                   const float* __restrict__ bias,
                                                   u16* __restrict__ Y) {
  __shared__ __align__(16) u16 Asub[2][128 * 40];
  __shared__ __align__(16) u16 Bsub[2][128 * 40];
  const int t = threadIdx.x;
  const int lane = t & 63;
  const int w = t >> 6;
  const int l16 = lane & 15;
  const int ko8 = (lane >> 4) * 8;
  const int m0 = blockIdx.y * 128;
  const int n0 = blockIdx.x * 128;
  const int wr = (w >> 1) * 64, wc = (w & 1) * 64;
  f32x4 acc[4][4] = {};

  float4 areg[4];
  int4 breg[2];
  // addressing (verified R1 pattern): A chunk c=t+256p -> row c>>3, col (c&7)*4
  //                                   B chunk c=t+256p -> row c>>2, col (c&3)*8
#define PLOAD(kt)                                                              \
  {                                                                            \
    const int k0_ = (kt) * 32;                                                 \
    _Pragma("unroll")                                                          \
    for (int p = 0; p < 4; ++p) {                                              \
      int c = t + 256 * p;                                                     \
      areg[p] = *(const float4*)&X[(size_t)(m0 + (c >> 3)) * NC + k0_ + (c & 7) * 4]; \
    }                                                                          \
    _Pragma("unroll")                                                          \
    for (int p = 0; p < 2; ++p) {                                              \
      int c = t + 256 * p;                                                     \
      breg[p] = *(const int4*)&WT[(size_t)(n0 + (c >> 2)) * NC + k0_ + (c & 3) * 8];  \
    }                                                                          \
  }
#define PWRITE(buf)                                                            \
  {                                                                            \
    _Pragma("unroll")                                                          \
    for (int p = 0; p < 4; ++p) {                                              \
      int c = t + 256 * p;                                                     \
      ushort4 bb;                                                              \
      bb.x = f2bf(areg[p].x); bb.y = f2bf(areg[p].y);                          \
      bb.z = f2bf(areg[p].z); bb.w = f2bf(areg[p].w);                          \
      *(ushort4*)&Asub[buf][(c >> 3) * 40 + (c & 7) * 4] = bb;                 \
    }                                                                          \
    _Pragma("unroll")                                                          \
    for (int p = 0; p < 2; ++p) {                                              \
      int c = t + 256 * p;                                                     \
      *(int4*)&Bsub[buf][(c >> 2) * 40 + (c & 3) * 8] = breg[p];               \
    }                                                                          \
  }

  PLOAD(0)
  PWRITE(0)
  __syncthreads();

  int pb = 0;
  for (int kt = 0; kt < 16; ++kt) {
    if (kt < 15) PLOAD(kt + 1)          // in flight during compute
    s16x8 af[4], bf[4];
#pragma unroll
    for (int i = 0; i < 4; ++i)
      af[i] = *(const s16x8*)&Asub[pb][(wr + i * 16 + l16) * 40 + ko8];
#pragma unroll
    for (int j = 0; j < 4; ++j)
      bf[j] = *(const s16x8*)&Bsub[pb][(wc + j * 16 + l16) * 40 + ko8];
#pragma unroll
    for (int i = 0; i < 4; ++i)
#pragma unroll
      for (int j = 0; j < 4; ++j)
        acc[i][j] = __builtin_amdgcn_mfma_f32_16x16x32_bf16(af[i], bf[j], acc[i][j], 0, 0, 0);
    if (kt < 15) PWRITE(pb ^ 1)         // waits vmcnt, lands in other buffer
    __syncthreads();
    pb ^= 1;
  }
#undef PLOAD
#undef PWRITE
  const int rg = (lane >> 4) * 4;
#pragma unroll
  for (int i = 0; i < 4; ++i)
#pragma unroll
    for (int j = 0; j < 4; ++j) {
      const int col = n0 + wc + j * 16 + l16;
      const float bcol = bias[col];
#pragma unroll
      for (int jj = 0; jj < 4; ++jj) {
        const int row = m0 + wr + i * 16 + rg + jj;
        Y[(size_t)row * NH + col] = f2bf(acc[i][j][jj] + bcol);
      }
    }
}

// ---------------- K2: Vp [B][T][H] bf16 -> VpT [B][H][T] bf16 ----------------
__global__ __launch_bounds__(256) void vt_kernel(const u16* __restrict__ Vp,
                                                 u16* __restrict__ VpT) {
  __shared__ u16 tile[32][33];
  const int x = threadIdx.x & 31;
  const int y = threadIdx.x >> 5;
  const int t0 = blockIdx.x * 32, h0 = blockIdx.y * 32, b = blockIdx.z;
  const u16* src = Vp + (size_t)b * NT * NH;
  u16* dst = VpT + (size_t)b * NH * NT;
#pragma unroll
  for (int p = 0; p < 4; ++p)
    tile[y + 8 * p][x] = src[(size_t)(t0 + y + 8 * p) * NH + h0 + x];
  __syncthreads();
#pragma unroll
  for (int p = 0; p < 4; ++p)
    dst[(size_t)(h0 + y + 8 * p) * NT + t0 + x] = tile[x][y + 8 * p];
}

// ---------------- K3a: flash partial, QB=128, 2-way kv-split ----------------
// grid (NB=8, NT/128=16, 2). block 512 = 8 waves, each owns 16 q rows.
// KVBLK=32, double-buffered K+V LDS (128 KB). T5 setprio around MFMA
// clusters; T13 defer-max with THR=8 (rescale only when max grows > 8).
__global__ __launch_bounds__(512, 2) void flash_partial(const u16* __restrict__ Qp,
                                                        const u16* __restrict__ Kp,
                                                        const u16* __restrict__ VpT,
                                                        float* __restrict__ O0,
                                                        float* __restrict__ O1,
                                                        float* __restrict__ mlws) {
  __shared__ __align__(16) u16 Klds[2][32 * 512];   // 32 KB each
  __shared__ __align__(16) u16 Vlds[2][32 * 512];   // 32 KB each

  const int t = threadIdx.x;
  const int lane = t & 63;
  const int w = t >> 6;               // 0..7: q-group
  const int l16 = lane & 15;
  const int g = lane >> 4;
  const int g8 = g * 8;
  const int b = blockIdx.x;
  const int q0 = blockIdx.y * 128;
  const int z = blockIdx.z;
  const int qg = q0 + w * 16 + l16;   // this lane's q row
  const float kscale = 0.044194173824159216f;  // 1/sqrt(512)

  // Q fragments (B-operand): lane holds Q[q=l16][d = ks*32 + g*8 .. +7]
  s16x8 qf[16];
  {
    const u16* qrow = Qp + (size_t)(b * NT + qg) * NH;
#pragma unroll
    for (int ks = 0; ks < 16; ++ks)
      qf[ks] = *(const s16x8*)&qrow[ks * 32 + g8];
  }

  f32x4 oacc[32] = {};                 // O^T: h = ht*16 + g*4 + j, q = l16
  float m_run = -1e30f, l_run = 0.f;

  const u16* kbat = Kp + (size_t)(b * NT + z * 1024) * NH;
  const u16* vbat = VpT + (size_t)b * NH * NT + z * 1024;

  // stage tile 'it' into buffer buf: 64 gld16 per block = 8 per wave (4K+4V)
#define STAGE(buf, it)                                                         \
  {                                                                            \
    _Pragma("unroll")                                                          \
    for (int r = 0; r < 4; ++r) {                                              \
      const int i = w * 4 + r;  /* 0..31 */                                    \
      gld16(kbat + (size_t)((it) * 32 + ((i & 1) << 4) + l16) * NH             \
                 + ((i >> 1) << 5) + g8,                                       \
            &Klds[buf][i * 512]);                                              \
      gld16(vbat + (size_t)(i * 16 + l16) * NT + (it) * 32 + g8,               \
            &Vlds[buf][i * 512]);                                              \
    }                                                                          \
  }

  STAGE(0, 0)
  __syncthreads();

  int pb = 0;
  for (int it = 0; it < 32; ++it) {
    if (it < 31) STAGE(pb ^ 1, it + 1)
    // ---- QK^T: S^T[32 kv][16 q] ----
    f32x4 s0 = {}, s1 = {};
    __builtin_amdgcn_s_setprio(1);
#pragma unroll
    for (int ks = 0; ks < 16; ++ks) {
      s16x8 kf0 = *(const s16x8*)&Klds[pb][(ks * 2 + 0) * 512 + lane * 8];
      s16x8 kf1 = *(const s16x8*)&Klds[pb][(ks * 2 + 1) * 512 + lane * 8];
      s0 = __builtin_amdgcn_mfma_f32_16x16x32_bf16(kf0, qf[ks], s0, 0, 0, 0);
      s1 = __builtin_amdgcn_mfma_f32_16x16x32_bf16(kf1, qf[ks], s1, 0, 0, 0);
    }
    __builtin_amdgcn_s_setprio(0);
    // ---- softmax (in-register; lane's q = l16) ----
    float pv[8];
#pragma unroll
    for (int j = 0; j < 4; ++j) { pv[j] = s0[j] * kscale; pv[4 + j] = s1[j] * kscale; }
    float mx = pv[0];
#pragma unroll
    for (int j = 1; j < 8; ++j) mx = fmaxf(mx, pv[j]);
    mx = fmaxf(mx, __shfl_xor(mx, 16, 64));
    mx = fmaxf(mx, __shfl_xor(mx, 32, 64));
    // T13 defer-max: rescale only when max grows by > 8 (P bounded by e^8)
    if (__any(mx > m_run + 8.f)) {
      const float m_new = fmaxf(m_run, mx);
      const float scale = __expf(m_run - m_new);
#pragma unroll
      for (int ht = 0; ht < 32; ++ht) {
        oacc[ht][0] *= scale; oacc[ht][1] *= scale;
        oacc[ht][2] *= scale; oacc[ht][3] *= scale;
      }
      l_run *= scale;
      m_run = m_new;
    }
    float ts = 0.f;
#pragma unroll
    for (int j = 0; j < 8; ++j) { pv[j] = __expf(pv[j] - m_run); ts += pv[j]; }
    ts += __shfl_xor(ts, 16, 64);
    ts += __shfl_xor(ts, 32, 64);
    l_run += ts;
    // ---- P^T -> B-operand fragment (8 shuffles, verified R4 path) ----
    u32 b0 = ((u32)f2bf(pv[1]) << 16) | f2bf(pv[0]);
    u32 b1 = ((u32)f2bf(pv[3]) << 16) | f2bf(pv[2]);
    u32 b2 = ((u32)f2bf(pv[5]) << 16) | f2bf(pv[4]);
    u32 b3 = ((u32)f2bf(pv[7]) << 16) | f2bf(pv[6]);
    const int srcA = (g & 1) * 32 + l16;
    const int srcB = srcA + 16;
    u32 x0 = (u32)__shfl((int)b0, srcA, 64);
    u32 x1 = (u32)__shfl((int)b1, srcA, 64);
    u32 x2 = (u32)__shfl((int)b2, srcA, 64);
    u32 x3 = (u32)__shfl((int)b3, srcA, 64);
    u32 y0 = (u32)__shfl((int)b0, srcB, 64);
    u32 y1 = (u32)__shfl((int)b1, srcB, 64);
    u32 y2 = (u32)__shfl((int)b2, srcB, 64);
    u32 y3 = (u32)__shfl((int)b3, srcB, 64);
    const bool hi = (lane >> 5) & 1;
    union { u32 u[4]; s16x8 v; } pf;
    pf.u[0] = hi ? x2 : x0;
    pf.u[1] = hi ? x3 : x1;
    pf.u[2] = hi ? y2 : y0;
    pf.u[3] = hi ? y3 : y1;
    // ---- PV: O^T[h][q] += V^T[h][kv] @ P^T[kv][q] ----
    __builtin_amdgcn_s_setprio(1);
#pragma unroll
    for (int ht = 0; ht < 32; ++ht) {
      s16x8 vf = *(const s16x8*)&Vlds[pb][ht * 512 + lane * 8];
      oacc[ht] = __builtin_amdgcn_mfma_f32_16x16x32_bf16(vf, pf.v, oacc[ht], 0, 0, 0);
    }
    __builtin_amdgcn_s_setprio(0);
    __syncthreads();
    pb ^= 1;
  }
  // ---- epilogue: UNNORMALIZED O + (m,l) ----
  float* obase = (z ? O1 : O0) + (size_t)(b * NT + qg) * NH;
#pragma unroll
  for (int ht = 0; ht < 32; ++ht) {
    float4 st;
    st.x = oacc[ht][0]; st.y = oacc[ht][1];
    st.z = oacc[ht][2]; st.w = oacc[ht][3];
    *(float4*)&obase[ht * 16 + g * 4] = st;
  }
  if (g == 0) {
    const size_t row = (size_t)b * NT + qg;
    mlws[row * 4 + z * 2 + 0] = m_run;
    mlws[row * 4 + z * 2 + 1] = l_run;
  }
#undef STAGE
}

// ---------------- K3b: merge two kv-half partials ----------------
__global__ __launch_bounds__(128) void merge_kernel(float* __restrict__ out,
                                                    const float* __restrict__ O1,
                                                    const float* __restrict__ mlws) {
  const size_t row = blockIdx.x;
  const float m0 = mlws[row * 4 + 0], l0 = mlws[row * 4 + 1];
  const float m1 = mlws[row * 4 + 2], l1 = mlws[row * 4 + 3];
  const float m = fmaxf(m0, m1);
  const float a0 = __expf(m0 - m), a1 = __expf(m1 - m);
  const float inv = 1.f / (a0 * l0 + a1 * l1);
  const float c0 = a0 * inv, c1 = a1 * inv;
  const size_t idx = row * NH + threadIdx.x * 4;
  float4 o0 = *(const float4*)&out[idx];
  float4 o1 = *(const float4*)&O1[idx];
  float4 r;
  r.x = c0 * o0.x + c1 * o1.x;
  r.y = c0 * o0.y + c1 * o1.y;
  r.z = c0 * o0.z + c1 * o1.z;
  r.w = c0 * o0.w + c1 * o1.w;
  *(float4*)&out[idx] = r;
}

// ---------------- K3-fallback: R4 single-pass flash (if ws too small) --------
__global__ __launch_bounds__(256, 1) void flash_kernel(const u16* __restrict__ Qp,
                                                       const u16* __restrict__ Kp,
                                                       const u16* __restrict__ VpT,
                                                       float* __restrict__ out) {
  __shared__ __align__(16) u16 Klds[2][32 * 512];
  __shared__ __align__(16) u16 Vlds[2][32 * 512];

  const int t = threadIdx.x;
  const int lane = t & 63;
  const int w = t >> 6;
  const int l16 = lane & 15;
  const int g = lane >> 4;
  const int g8 = g * 8;
  const int b = blockIdx.x;
  const int q0 = blockIdx.y * 64;
  const int qg = q0 + w * 16 + l16;
  const float kscale = 0.044194173824159216f;

  s16x8 qf[16];
  {
    const u16* qrow = Qp + (size_t)(b * NT + qg) * NH;
#pragma unroll
    for (int ks = 0; ks < 16; ++ks)
      qf[ks] = *(const s16x8*)&qrow[ks * 32 + g8];
  }
  f32x4 oacc[32] = {};
  float m_run = -1e30f, l_run = 0.f;
  const u16* kbat = Kp + (size_t)b * NT * NH;
  const u16* vbat = VpT + (size_t)b * NH * NT;

#pragma unroll
  for (int r = 0; r < 8; ++r) {
    const int i = w * 8 + r;
    gld16(kbat + (size_t)(((i & 1) << 4) + l16) * NH + ((i >> 1) << 5) + g8,
          &Klds[0][i * 512]);
    gld16(vbat + (size_t)(i * 16 + l16) * NT + g8, &Vlds[0][i * 512]);
  }
  __syncthreads();

  int pb = 0;
  for (int it = 0; it < 64; ++it) {
    if (it < 63) {
      const int kv1 = (it + 1) * 32;
      const int nb = pb ^ 1;
#pragma unroll
      for (int r = 0; r < 8; ++r) {
        const int i = w * 8 + r;
        gld16(kbat + (size_t)(kv1 + ((i & 1) << 4) + l16) * NH + ((i >> 1) << 5) + g8,
              &Klds[nb][i * 512]);
        gld16(vbat + (size_t)(i * 16 + l16) * NT + kv1 + g8, &Vlds[nb][i * 512]);
      }
    }
    f32x4 s0 = {}, s1 = {};
#pragma unroll
    for (int ks = 0; ks < 16; ++ks) {
      s16x8 kf0 = *(const s16x8*)&Klds[pb][(ks * 2 + 0) * 512 + lane * 8];
      s16x8 kf1 = *(const s16x8*)&Klds[pb][(ks * 2 + 1) * 512 + lane * 8];
      s0 = __builtin_amdgcn_mfma_f32_16x16x32_bf16(kf0, qf[ks], s0, 0, 0, 0);
      s1 = __builtin_amdgcn_mfma_f32_16x16x32_bf16(kf1, qf[ks], s1, 0, 0, 0);
    }
    float pv[8];
#pragma unroll
    for (int j = 0; j < 4; ++j) { pv[j] = s0[j] * kscale; pv[4 + j] = s1[j] * kscale; }
    float mx = pv[0];
#pragma unroll
    for (int j = 1; j < 8; ++j) mx = fmaxf(mx, pv[j]);
    mx = fmaxf(mx, __shfl_xor(mx, 16, 64));
    mx = fmaxf(mx, __shfl_xor(mx, 32, 64));
    if (__any(mx > m_run)) {
      const float m_new = fmaxf(m_run, mx);
      const float scale = __expf(m_run - m_new);
#pragma unroll
      for (int ht = 0; ht < 32; ++ht) {
        oacc[ht][0] *= scale; oacc[ht][1] *= scale;
        oacc[ht][2] *= scale; oacc[ht][3] *= scale;
      }
      l_run *= scale;
      m_run = m_new;
    }
    float ts = 0.f;
#pragma unroll
    for (int j = 0; j < 8; ++j) { pv[j] = __expf(pv[j] - m_run); ts += pv[j]; }
    ts += __shfl_xor(ts, 16, 64);
    ts += __shfl_xor(ts, 32, 64);
    l_run += ts;
    u32 b0 = ((u32)f2bf(pv[1]) << 16) | f2bf(pv[0]);
    u32 b1 = ((u32)f2bf(pv[3]) << 16) | f2bf(pv[2]);
    u32 b2 = ((u32)f2bf(pv[5]) << 16) | f2bf(pv[4]);
    u32 b3 = ((u32)f2bf(pv[7]) << 16) | f2bf(pv[6]);
    const int srcA = (g & 1) * 32 + l16;
    const int srcB = srcA + 16;
    u32 x0 = (u32)__shfl((int)b0, srcA, 64);
    u32 x1 = (u32)__shfl((int)b1, srcA, 64);
    u32 x2 = (u32)__shfl((int)b2, srcA, 64);
    u32 x3 = (u32)__shfl((int)b3, srcA, 64);
    u32 y0 = (u32)__shfl((int)b0, srcB, 64);
    u32 y1 = (u32)__shfl((int)b1, srcB, 64);
    u32 y2 = (u32)__shfl((int)b2, srcB, 64);
    u32 y3 = (u32)__shfl((int)b3, srcB, 64);
    const bool hi = (lane >> 5) & 1;
    union { u32 u[4]; s16x8 v; } pf;
    pf.u[0] = hi ? x2 : x0;
    pf.u[1] = hi ? x3 : x1;
    pf.u[2] = hi ? y2 : y0;
    pf.u[3] = hi ? y3 : y1;
#pragma unroll
    for (int ht = 0; ht < 32; ++ht) {
      s16x8 vf = *(const s16x8*)&Vlds[pb][ht * 512 + lane * 8];
      oacc[ht] = __builtin_amdgcn_mfma_f32_16x16x32_bf16(vf, pf.v, oacc[ht], 0, 0, 0);
    }
    __syncthreads();
    pb ^= 1;
  }
  const float inv = 1.f / l_run;
  float* obase = out + (size_t)(b * NT + qg) * NH;
#pragma unroll
  for (int ht = 0; ht < 32; ++ht) {
    float4 st;
    st.x = oacc[ht][0] * inv; st.y = oacc[ht][1] * inv;
    st.z = oacc[ht][2] * inv; st.w = oacc[ht][3] * inv;
    *(float4*)&obase[ht * 16 + g * 4] = st;
  }
}

extern "C" void kernel_launch(void* const* d_in, const int* in_sizes, int n_in,
                              void* d_out, int out_size, void* d_ws, size_t ws_size,
                              hipStream_t stream) {
  (void)in_sizes; (void)n_in; (void)out_size;
  const float* q  = (const float*)d_in[0];
  const float* k  = (const float*)d_in[1];
  const float* v  = (const float*)d_in[2];
  const float* Wq = (const float*)d_in[3];
  const float* bq = (const float*)d_in[4];
  const float* Wk = (const float*)d_in[5];
  const float* bk = (const float*)d_in[6];
  const float* Wv = (const float*)d_in[7];
  const float* bv = (const float*)d_in[8];
  float* out = (float*)d_out;

  u16* ws   = (u16*)d_ws;
  u16* WqT  = ws;
  u16* WkT  = WqT + (size_t)NC * NH;
  u16* WvT  = WkT + (size_t)NC * NH;
  u16* Qp   = WvT + (size_t)NC * NH;
  u16* Kp   = Qp + (size_t)NB * NT * NH;
  u16* Vp   = Kp + (size_t)NB * NT * NH;
  u16* VpT  = Vp + (size_t)NB * NT * NH;
  u16* endb = VpT + (size_t)NB * NT * NH;
  // kv-split extras: O1 partial (f32, 32 MB) + mlws (4 f32/row)
  float* O1   = (float*)endb;
  float* mlws = O1 + (size_t)NB * NT * NH;
  const size_t need = (size_t)((char*)(mlws + (size_t)NB * NT * 4) - (char*)d_ws);

  wt_kernel<<<dim3(16, 16), 256, 0, stream>>>(Wq, WqT);
  wt_kernel<<<dim3(16, 16), 256, 0, stream>>>(Wk, WkT);
  wt_kernel<<<dim3(16, 16), 256, 0, stream>>>(Wv, WvT);

  proj_kernel<<<dim3(4, 128), 256, 0, stream>>>(q, WqT, bq, Qp);
  proj_kernel<<<dim3(4, 128), 256, 0, stream>>>(k, WkT, bk, Kp);
  proj_kernel<<<dim3(4, 128), 256, 0, stream>>>(v, WvT, bv, Vp);

  vt_kernel<<<dim3(64, 16, NB), 256, 0, stream>>>(Vp, VpT);

  if (ws_size >= need) {
    flash_partial<<<dim3(NB, NT / 128, 2), 512, 0, stream>>>(Qp, Kp, VpT, out, O1, mlws);
    merge_kernel<<<dim3(NB * NT), 128, 0, stream>>>(out, O1, mlws);
  } else {
    flash_kernel<<<dim3(NB, NT / 64), 256, 0, stream>>>(Qp, Kp, VpT, out);
  }
}